// Round 1
// baseline (2924.605 us; speedup 1.0000x reference)
//
#include <hip/hip_runtime.h>

// ============================================================================
// Tatt: temp construction (analytic roll-collapse) -> 3x gated GCN (f16 MFMA
// GEMM + banded A-mul + tanh*sigmoid) -> Conv1d(k=577) as implicit-im2col f16
// MFMA GEMM with split-K=2 -> reduce+transpose epilogue.
//
// Dims: B=32, T1=288, T3=864, N=H=325 (pad K->352 "IPAD", pad N->384 "NPAD"),
// KSIZE=577. Conv GEMM: M=9216, N=384(pad), Kflat=577*352=203104 (pad 203136).
// ============================================================================

typedef _Float16 half8 __attribute__((ext_vector_type(8)));
typedef float floatx4 __attribute__((ext_vector_type(4)));

#define DEV __device__ __forceinline__
#define AS1 __attribute__((address_space(1)))
#define AS3 __attribute__((address_space(3)))

constexpr int IPAD = 352;                 // padded inner (sensor) dim
constexpr int NPAD = 384;                 // padded outer (channel) dim
constexpr int MGCN = 32 * 864;            // 27648
constexpr int MCONV = 32 * 288;           // 9216
constexpr int KCONV_PAD = 203136;         // 3174 * 64  (>= 577*352 = 203104)
constexpr int CH_CONV = KCONV_PAD / 64;   // 3174
constexpr int CONV_SPLITS = 2;
constexpr int CH_SPLIT = CH_CONV / CONV_SPLITS;  // 1587

// ---- workspace layout (bytes) ----
constexpr size_t OFF_XG = 0;                                   // f16 [27649][352]
constexpr size_t SZ_XG_AL = 19465216;                          // 27649*352*2 = 19464896, aligned
constexpr size_t SZ_S = (size_t)MGCN * NPAD * 4;               // 42467328
constexpr size_t OFF_S1 = OFF_XG + SZ_XG_AL;
constexpr size_t OFF_S2 = OFF_S1 + SZ_S;
constexpr size_t OFF_WG = OFF_S2 + SZ_S;                       // 6 * [384][384] f16
constexpr size_t SZ_WG = 6ull * NPAD * NPAD * 2;               // 1769472
constexpr size_t OFF_WCONV = OFF_WG + SZ_WG;                   // [384][203136] f16
constexpr size_t OFF_CPART = OFF_S1;                           // alias (2 slices of [9216][384] f32)
// total = OFF_WCONV + 384*203136*2 = 262,177,792 bytes

DEV void gload16(const void* g, void* l) {
    __builtin_amdgcn_global_load_lds((const AS1 void*)g, (AS3 void*)l, 16, 0, 0);
}

// ---------------------------------------------------------------------------
// temp:  Xg[b*864+m][i] = (m in [288,576)) ? IF[b][i][m-288]
//                        : x[(m + s_b + 1728) % 2016][i],   0 for i>=325
// ---------------------------------------------------------------------------
__global__ void k_temp(const float* __restrict__ IF, const float* __restrict__ x,
                       const int* __restrict__ week, const int* __restrict__ hour,
                       _Float16* __restrict__ Xg) {
    int idx = blockIdx.x * 256 + threadIdx.x;       // over 27648*352
    if (idx >= MGCN * IPAD) return;
    int i  = idx % IPAD;
    int mm = idx / IPAD;
    int m  = mm % 864, b = mm / 864;
    float v = 0.f;
    if (i < 325) {
        if (m >= 288 && m < 576) {
            v = IF[((size_t)b * 325 + i) * 288 + (m - 288)];
        } else {
            int s  = week[b] * 288 + hour[b];
            int tm = (m + s + 1728) % 2016;
            v = x[(size_t)tm * 325 + i];
        }
    }
    Xg[(size_t)mm * IPAD + i] = (_Float16)v;
}

// ---------------------------------------------------------------------------
// pack 6 GCN weights, transposed + zero-padded:  Wg[l][o][d] = w_l[d*325+o]
// ---------------------------------------------------------------------------
__global__ void k_pack_gcn(const float* w0, const float* w1, const float* w2,
                           const float* w3, const float* w4, const float* w5,
                           _Float16* __restrict__ Wg) {
    int idx = blockIdx.x * 256 + threadIdx.x;       // 6*384*384
    int d = idx % NPAD;
    int o = (idx / NPAD) % NPAD;
    int l = idx / (NPAD * NPAD);
    const float* w = l == 0 ? w0 : l == 1 ? w1 : l == 2 ? w2 : l == 3 ? w3 : l == 4 ? w4 : w5;
    float v = (o < 325 && d < 325) ? w[d * 325 + o] : 0.f;
    Wg[(size_t)idx] = (_Float16)v;
}

// ---------------------------------------------------------------------------
// pack conv weights:  Wc[o][k*352+i] = conv_w[o][i][k]  (zero-padded)
// 32x32 LDS-transpose tiles: read coalesced along k, write coalesced along i.
// ---------------------------------------------------------------------------
__global__ void k_pack_conv(const float* __restrict__ cw, _Float16* __restrict__ Wc) {
    __shared__ float tile[32][33];
    int o = blockIdx.x, i0 = blockIdx.y * 32, k0 = blockIdx.z * 32;
    int t = threadIdx.x;
    int c = t & 31, r4 = t >> 5;
#pragma unroll
    for (int p = 0; p < 4; ++p) {
        int ii = r4 * 4 + p;
        int i = i0 + ii, k = k0 + c;
        float v = 0.f;
        if (o < 325 && i < 325 && k < 577) v = cw[((size_t)o * 325 + i) * 577 + k];
        tile[ii][c] = v;
    }
    __syncthreads();
#pragma unroll
    for (int p = 0; p < 4; ++p) {
        int kk = r4 * 4 + p;
        int k = k0 + kk, i = i0 + c;
        int kidx = k * IPAD + i;
        if (kidx < KCONV_PAD) Wc[(size_t)o * KCONV_PAD + kidx] = (_Float16)tile[c][kk];
    }
}

// ---------------------------------------------------------------------------
// f16 MFMA GEMM, 128x128 tile, BK=64, global_load_lds staging with XOR swizzle.
// C[m][n] = sum_K A[m][K] * Bw[n][K]   (Bw packed row-major [n][K])
// CONV: A row address = (m + (m/288)*576)*352 + kidx  (implicit im2col; pure
//       pointer increment of 64 elems per 64-chunk thanks to (k,i) flattening)
// ---------------------------------------------------------------------------
template <bool CONV>
__global__ __launch_bounds__(256) void k_gemm(const _Float16* __restrict__ Xg,
                                              const _Float16* __restrict__ Bw,
                                              float* __restrict__ C,
                                              int bStride, int chunksPerSplit,
                                              int chunksTotal, long long sliceStride) {
    __shared__ _Float16 sA[128 * 64];
    __shared__ _Float16 sB[128 * 64];
    const int t = threadIdx.x;
    const int m0 = blockIdx.x * 128, n0 = blockIdx.y * 128;
    const int bz = blockIdx.z;
    int chunk0 = bz * chunksPerSplit;
    int nch = chunksTotal - chunk0;
    if (nch > chunksPerSplit) nch = chunksPerSplit;
    C += (size_t)bz * (size_t)sliceStride;

    // staging pointers: thread t stages LDS 16B-block (j*256+t); LDS block
    // position (row, c=t&7) holds GLOBAL block (c ^ (row&7))  [XOR swizzle]
    const int rj = t >> 3;
    const int cg = (t & 7) ^ (rj & 7);
    const _Float16* pa[4];
    const _Float16* pb[4];
#pragma unroll
    for (int j = 0; j < 4; ++j) {
        int m = m0 + j * 32 + rj;
        int mrow = CONV ? (m + (m / 288) * 576) : m;
        pa[j] = Xg + (size_t)mrow * IPAD + (size_t)chunk0 * 64 + cg * 8;
        int n = n0 + j * 32 + rj;
        pb[j] = Bw + (size_t)n * bStride + (size_t)chunk0 * 64 + cg * 8;
    }

    const int lane = t & 63, wv = t >> 6;
    const int wm = wv >> 1, wn = wv & 1;            // 2x2 waves of 64x64
    const int r = lane & 15, q = lane >> 4, s8 = r & 7;
    int aRow[4], bRow[4];
#pragma unroll
    for (int i = 0; i < 4; ++i) {
        aRow[i] = (wm * 64 + i * 16 + r) * 64;
        bRow[i] = (wn * 64 + i * 16 + r) * 64;
    }
    const int xk0 = (q ^ s8) * 8;                   // swizzled 16B-block offsets
    const int xk1 = ((q + 4) ^ s8) * 8;

    floatx4 acc[4][4] = {};

    for (int ch = 0; ch < nch; ++ch) {
        __syncthreads();
#pragma unroll
        for (int j = 0; j < 4; ++j) { gload16(pa[j], &sA[(j * 256 + t) * 8]); pa[j] += 64; }
#pragma unroll
        for (int j = 0; j < 4; ++j) { gload16(pb[j], &sB[(j * 256 + t) * 8]); pb[j] += 64; }
        __syncthreads();
#pragma unroll
        for (int kk = 0; kk < 2; ++kk) {
            const int xk = kk ? xk1 : xk0;
            half8 av[4], bv[4];
#pragma unroll
            for (int mi = 0; mi < 4; ++mi) av[mi] = *(const half8*)(sA + aRow[mi] + xk);
#pragma unroll
            for (int ni = 0; ni < 4; ++ni) bv[ni] = *(const half8*)(sB + bRow[ni] + xk);
#pragma unroll
            for (int mi = 0; mi < 4; ++mi)
#pragma unroll
                for (int ni = 0; ni < 4; ++ni)
                    acc[mi][ni] = __builtin_amdgcn_mfma_f32_16x16x32_f16(av[mi], bv[ni],
                                                                         acc[mi][ni], 0, 0, 0);
        }
    }

    // C/D layout: col = lane&15, row = (lane>>4)*4 + reg   [m89-verified]
#pragma unroll
    for (int mi = 0; mi < 4; ++mi)
#pragma unroll
        for (int ni = 0; ni < 4; ++ni) {
            int row = m0 + wm * 64 + mi * 16 + q * 4;
            int col = n0 + wn * 64 + ni * 16 + r;
#pragma unroll
            for (int e = 0; e < 4; ++e)
                C[(size_t)(row + e) * NPAD + col] = acc[mi][ni][e];
        }
}

// ---------------------------------------------------------------------------
// banded D^-1/2 A D^-1/2 (7-diag) + bias + tanh*sigmoid -> f16 Xg (in place)
// ---------------------------------------------------------------------------
__global__ void k_bandact(const float* __restrict__ S1, const float* __restrict__ S2,
                          const float* __restrict__ b1, const float* __restrict__ b2,
                          _Float16* __restrict__ Xg) {
    int bm = blockIdx.x;                            // 0..27647
    int m = bm % 864;
    int dm = (m < 3 ? m : 3) + ((863 - m) < 3 ? (863 - m) : 3) + 1;
    for (int o = threadIdx.x; o < 325; o += 256) {
        float g1 = b1[o], g2 = b2[o];
#pragma unroll
        for (int dn = -3; dn <= 3; ++dn) {
            int n = m + dn;
            if (n < 0 || n > 863) continue;
            int dnd = (n < 3 ? n : 3) + ((863 - n) < 3 ? (863 - n) : 3) + 1;
            float a = rsqrtf((float)(dm * dnd));
            size_t off = (size_t)(bm + dn) * NPAD + o;
            g1 += a * S1[off];
            g2 += a * S2[off];
        }
        float vt = tanhf(g1);
        float vs = 1.f / (1.f + expf(-g2));
        Xg[(size_t)bm * IPAD + o] = (_Float16)(vt * vs);
    }
}

// ---------------------------------------------------------------------------
// reduce split-K slices + conv bias, transpose [m=(b,t)][o] -> out[b][o][t]
// ---------------------------------------------------------------------------
__global__ void k_reduce(const float* __restrict__ Cp, const float* __restrict__ cb,
                         float* __restrict__ out) {
    __shared__ float tile[32][33];
    int b = blockIdx.x, t0 = blockIdx.y * 32, o0 = blockIdx.z * 32;
    int t = threadIdx.x;
    int c = t & 31, r4 = t >> 5;
#pragma unroll
    for (int p = 0; p < 4; ++p) {
        int tt = r4 * 4 + p;
        size_t mrow = (size_t)(b * 288 + t0 + tt) * NPAD + (o0 + c);
        tile[tt][c] = Cp[mrow] + Cp[(size_t)MCONV * NPAD + mrow];
    }
    __syncthreads();
#pragma unroll
    for (int p = 0; p < 4; ++p) {
        int oo = r4 * 4 + p;
        int o = o0 + oo;
        if (o < 325)
            out[((size_t)b * 325 + o) * 288 + t0 + c] = tile[c][oo] + cb[o];
    }
}

// ---------------------------------------------------------------------------
extern "C" void kernel_launch(void* const* d_in, const int* in_sizes, int n_in,
                              void* d_out, int out_size, void* d_ws, size_t ws_size,
                              hipStream_t stream) {
    const float* IF = (const float*)d_in[0];
    const float* x  = (const float*)d_in[1];
    const float* wg[6] = {(const float*)d_in[2],  (const float*)d_in[4],
                          (const float*)d_in[6],  (const float*)d_in[8],
                          (const float*)d_in[10], (const float*)d_in[12]};
    const float* bg[6] = {(const float*)d_in[3],  (const float*)d_in[5],
                          (const float*)d_in[7],  (const float*)d_in[9],
                          (const float*)d_in[11], (const float*)d_in[13]};
    const float* cw  = (const float*)d_in[14];
    const float* cb  = (const float*)d_in[15];
    const int* week  = (const int*)d_in[16];
    const int* hour  = (const int*)d_in[17];
    float* out = (float*)d_out;

    char* ws = (char*)d_ws;
    _Float16* Xg = (_Float16*)(ws + OFF_XG);
    float* S1    = (float*)(ws + OFF_S1);
    float* S2    = (float*)(ws + OFF_S2);
    _Float16* Wg = (_Float16*)(ws + OFF_WG);
    _Float16* Wc = (_Float16*)(ws + OFF_WCONV);
    float* Cp    = (float*)(ws + OFF_CPART);   // aliases S1/S2 (conv phase only)

    k_pack_gcn<<<(6 * NPAD * NPAD) / 256, 256, 0, stream>>>(wg[0], wg[1], wg[2], wg[3],
                                                            wg[4], wg[5], Wg);
    k_pack_conv<<<dim3(NPAD, 11, 19), 256, 0, stream>>>(cw, Wc);
    k_temp<<<(MGCN * IPAD) / 256, 256, 0, stream>>>(IF, x, week, hour, Xg);

    for (int l = 0; l < 3; ++l) {
        k_gemm<false><<<dim3(MGCN / 128, NPAD / 128, 1), 256, 0, stream>>>(
            Xg, Wg + (size_t)(2 * l) * NPAD * NPAD, S1, NPAD, 6, 6, 0);
        k_gemm<false><<<dim3(MGCN / 128, NPAD / 128, 1), 256, 0, stream>>>(
            Xg, Wg + (size_t)(2 * l + 1) * NPAD * NPAD, S2, NPAD, 6, 6, 0);
        k_bandact<<<MGCN, 256, 0, stream>>>(S1, S2, bg[2 * l], bg[2 * l + 1], Xg);
    }

    k_gemm<true><<<dim3(MCONV / 128, NPAD / 128, CONV_SPLITS), 256, 0, stream>>>(
        Xg, Wc, Cp, KCONV_PAD, CH_SPLIT, CH_CONV, (long long)MCONV * NPAD);

    k_reduce<<<dim3(32, 9, 11), 256, 0, stream>>>(Cp, cb, out);
}